// Round 9
// baseline (187.693 us; speedup 1.0000x reference)
//
#include <hip/hip_runtime.h>
#include <math.h>

#define B_ 8
#define T_ 1024
#define C_ 768
#define H_ 8
#define D_ 96
#define M_ (B_ * T_)     // 8192 tokens
#define N1_ (3 * C_)     // 2304
#define KD_ 768          // K of both GEMMs
#define QS_ 1536         // qkv row stride (Q+K only; V lives in vt)

typedef __bf16 bf16x8 __attribute__((ext_vector_type(8)));
typedef float f32x4 __attribute__((ext_vector_type(4)));
typedef float f32x16 __attribute__((ext_vector_type(16)));

__device__ __forceinline__ unsigned short f2bf(float f) {
  unsigned int u = __float_as_uint(f);
  u += 0x7FFF + ((u >> 16) & 1);          // round-to-nearest-even
  return (unsigned short)(u >> 16);
}

// async global->LDS, 16B per lane; LDS dest = uniform base + lane*16
__device__ __forceinline__ void load_lds16(const void* g, void* l) {
  __builtin_amdgcn_global_load_lds(
      (const __attribute__((address_space(1))) unsigned int*)g,
      (__attribute__((address_space(3))) unsigned int*)l, 16, 0, 0);
}

// ---------------------------------------------------------------------------
// Fused prep: blocks 0..6143 cast x to bf16 (1024 elems each);
// blocks 6144.. transpose W_attn / W_proj to [N][K] bf16.
// ---------------------------------------------------------------------------
__global__ __launch_bounds__(256) void prep_kernel(
    const float* __restrict__ x, unsigned short* __restrict__ xb,
    const float* __restrict__ Wa, unsigned short* __restrict__ WaT,
    const float* __restrict__ Wp, unsigned short* __restrict__ WpT) {
  __shared__ float Lt[32][33];
  int bid = blockIdx.x;
  if (bid < 6144) {
    int i = (bid * 256 + threadIdx.x) * 4;
    float4 v = *(const float4*)(x + i);
    ushort4 o;
    o.x = f2bf(v.x); o.y = f2bf(v.y); o.z = f2bf(v.z); o.w = f2bf(v.w);
    *(ushort4*)(xb + i) = o;
    return;
  }
  bid -= 6144;
  const float* W; unsigned short* WT; int Nd;
  if (bid < 1728) { W = Wa; WT = WaT; Nd = N1_; }
  else            { W = Wp; WT = WpT; Nd = C_; bid -= 1728; }
  const int r0 = (bid % 24) * 32;   // Kd
  const int c0 = (bid / 24) * 32;   // Nd
#pragma unroll
  for (int i = 0; i < 4; ++i) {
    int e = threadIdx.x + 256 * i;
    int r = e >> 5, c = e & 31;
    Lt[r][c] = W[(size_t)(r0 + r) * Nd + c0 + c];
  }
  __syncthreads();
#pragma unroll
  for (int i = 0; i < 4; ++i) {
    int e = threadIdx.x + 256 * i;
    int rr = e >> 5, cc = e & 31;
    WT[(size_t)(c0 + rr) * KD_ + r0 + cc] = f2bf(Lt[cc][rr]);
  }
}

// ---------------------------------------------------------------------------
// R16 GEMM (kept): m97 2-buffer 32KB pipeline + coalesced conflict-free
// swizzled staging (0 measured conflicts). At its structural floor: R16
// doubled residency (occ 15->26%) with zero dur change -> per-CU issue
// path saturated, not residency-bound. 564 TF on QKV.
// Staging: per wave 4 x 1KB gload_lds; each = 16 consecutive rows x 64B
// (full BK=32). Lane l -> row (l>>2), global 16B chunk (l&3)^((l>>4)&3);
// LDS dest lane-linear. Frag read slot q^((R>>2)&3) -- involution, 0 confl.
// Used for BOTH GEMMs (QKV: VSCAT scatters V cols to vt; proj: OUTF32).
// C/D frag: col = lane&31, row = (r&3)+8*(r>>2)+4*(lane>>5)  [m74/m101].
// ---------------------------------------------------------------------------
template <bool OUTF32, bool VSCAT>
__global__ __launch_bounds__(256, 4) void gemm_mfma_kernel(
    const unsigned short* __restrict__ A, const unsigned short* __restrict__ Bt,
    const float* __restrict__ bias, void* __restrict__ Cout,
    unsigned short* __restrict__ vt, int N,
    int sc_lim, float sc, int mmask, int mshift) {
  constexpr int NCH = 16;              // 1KB chunks per buffer (A 8 + B 8)
  constexpr int CPW = 4;               // chunks staged per wave
  __shared__ __align__(16) unsigned short Sb[2][NCH * 512];  // 2 x 16 KB
  const int tid = threadIdx.x;
  const int w = tid >> 6, l = tid & 63;
  const int l31 = l & 31, lh = l >> 5;
  const int bid = blockIdx.x;
  const int m0 = (bid & mmask) * 128, n0 = (bid >> mshift) * 128;
  const int wrb = (w >> 1) * 2;        // wave A-block base (32-row units)
  const int wnb = (w & 1) * 2;         // wave B-block base

  f32x16 acc[2][2];
#pragma unroll
  for (int i = 0; i < 2; ++i)
#pragma unroll
    for (int j = 0; j < 2; ++j)
#pragma unroll
      for (int r = 0; r < 16; ++r) acc[i][j][r] = 0.f;

  const unsigned short* gp[CPW];
#pragma unroll
  for (int i = 0; i < CPW; ++i) {
    const int c = w * CPW + i;
    const int rr = (c & 7) * 16 + (l >> 2);
    const int ck = 8 * ((l & 3) ^ ((l >> 4) & 3));
    gp[i] = (c < 8) ? A  + (size_t)(m0 + rr) * KD_ + ck
                    : Bt + (size_t)(n0 + rr) * KD_ + ck;
  }

  // prologue: stage tile 0 into buffer 0
#pragma unroll
  for (int i = 0; i < CPW; ++i) {
    load_lds16(gp[i], &Sb[0][(w * CPW + i) * 512]);
    gp[i] += 32;
  }
  asm volatile("s_waitcnt vmcnt(0)" ::: "memory");
  __builtin_amdgcn_s_barrier();
  asm volatile("" ::: "memory");

  const int rhi = l31 >> 4;            // (R&31)>>4
  const int rlo = (l31 & 15) * 32;     // (R&15)*32 ushorts
  const int rx  = (l31 >> 2) & 3;      // (R>>2)&3 (XOR term)

  int cur = 0;
  for (int k0 = 0; k0 < KD_; k0 += 32) {
    const bool more = (k0 + 32 < KD_);
    if (more) {
#pragma unroll
      for (int i = 0; i < CPW; ++i) {
        load_lds16(gp[i], &Sb[cur ^ 1][(w * CPW + i) * 512]);
        gp[i] += 32;
      }
    }

#pragma unroll
    for (int kh = 0; kh < 2; ++kh) {
      const int q = 2 * kh + lh;       // 16B chunk index within 64B row
      bf16x8 af[2], bfr[2];
#pragma unroll
      for (int mi = 0; mi < 2; ++mi)
        af[mi] = *(const bf16x8*)
            &Sb[cur][((wrb + mi) * 2 + rhi) * 512 + rlo + ((q ^ rx)) * 8];
#pragma unroll
      for (int ni = 0; ni < 2; ++ni)
        bfr[ni] = *(const bf16x8*)
            &Sb[cur][(8 + (wnb + ni) * 2 + rhi) * 512 + rlo + ((q ^ rx)) * 8];
#pragma unroll
      for (int mi = 0; mi < 2; ++mi)
#pragma unroll
        for (int ni = 0; ni < 2; ++ni)
          acc[mi][ni] = __builtin_amdgcn_mfma_f32_32x32x16_bf16(
              af[mi], bfr[ni], acc[mi][ni], 0, 0, 0);
    }

    if (more) {
      asm volatile("s_waitcnt vmcnt(0)" ::: "memory");
      asm volatile("" ::: "memory");
      __builtin_amdgcn_s_barrier();
      asm volatile("" ::: "memory");
    }
    cur ^= 1;
  }

  const bool vblock = VSCAT && (n0 >= 1536);
#pragma unroll
  for (int mi = 0; mi < 2; ++mi) {
    const int rowb = m0 + (wrb + mi) * 32 + 4 * lh;
#pragma unroll
    for (int ni = 0; ni < 2; ++ni) {
      const int col = n0 + (wnb + ni) * 32 + l31;
      const float bv = bias[col];
      if (!vblock) {
        const float mul = (col < sc_lim) ? sc : 1.f;
#pragma unroll
        for (int r = 0; r < 16; ++r) {
          const int row = rowb + (r & 3) + 8 * (r >> 2);
          float v = (acc[mi][ni][r] + bv) * mul;
          if (OUTF32)
            ((float*)Cout)[(size_t)row * N + col] = v;
          else
            ((unsigned short*)Cout)[(size_t)row * N + col] = f2bf(v);
        }
      } else {
        const int x = col - 1536;
        const int h = x / 96, d = x % 96;
#pragma unroll
        for (int r = 0; r < 16; ++r) {
          const int row = rowb + (r & 3) + 8 * (r >> 2);
          const int bb = row >> 10, t = row & 1023;
          vt[((size_t)(bb * H_ + h) * D_ + d) * T_ + t] =
              f2bf(acc[mi][ni][r] + bv);
        }
      }
    }
  }
}

// ---------------------------------------------------------------------------
// R17 flash causal attention: q-QUAD blocks. Each block = (bh, pj) handles
// two 128-row q-tiles {pj, 7-pj} (256 blocks, all resident at 2/CU, 18
// key-tile iters each -- balanced). Per iter each wave runs TWO 16-row
// q-subs (s=0: rows q0+w*16, s=1: rows q0+64+w*16) against ONE K/V LDS
// load: kf/vf fragments read once, used by both subs. ds_read_b128 per
// unit work drops 52->28 (attn was LDS-read-bound: 26 reads ~312cyc vs
// 26 MFMA ~125cyc); staging + barriers halved.
// Causal: sub s is FULL for jt<2qt+s, DIAG at jt==2qt+s (nb/w mask),
// MASKED (Pt zeros) for s=0 at jt==2qt+1. nt = 2qt+2 key-tiles.
// Max-free softmax (Q pre-scaled), l via ones-MFMA, K/V dbuf LDS.
// ---------------------------------------------------------------------------
__global__ __launch_bounds__(256) void attn_mfma_kernel(
    const unsigned short* __restrict__ qkv,  // [8192][QS_], Q pre-scaled
    const unsigned short* __restrict__ vt,   // [64][96][1024]
    unsigned short* __restrict__ y) {        // [8192][768]
  __shared__ __align__(16) unsigned short KV[2][24 * 512];   // 48 KB
  __shared__ __align__(16) unsigned short Pt[2][4][16][72];  // 18.4 KB

  const int tid = threadIdx.x;
  const int w = tid >> 6, l = tid & 63;
  const int lm = l & 15, lq = l >> 4;
  const int bh = blockIdx.x & 63, pj = blockIdx.x >> 6;   // pj in [0,4)
  const int b = bh >> 3, h = bh & 7;
  const size_t bT = (size_t)b * T_;

  bf16x8 onef;
#pragma unroll
  for (int i = 0; i < 8; ++i) onef[i] = (__bf16)1.0f;

  auto issue = [&](int j0, int buf) {
#pragma unroll
    for (int i = 0; i < 6; ++i) {
      const int c = w * 6 + i;
      const unsigned short* g;
      if (c < 12) {
        const int kc = c >> 2, nb = c & 3;
        g = qkv + (bT + j0 + nb * 16 + lm) * QS_ + C_ + h * D_ + kc * 32 + lq * 8;
      } else {
        const int cv = c - 12;
        const int db = cv >> 1, vc = cv & 1;
        g = vt + ((size_t)bh * D_ + db * 16 + lm) * T_ + j0 + vc * 32 + lq * 8;
      }
      load_lds16(g, &KV[buf][c * 512]);
    }
  };

  int cur = 0;
  issue(0, 0);

  for (int half = 0; half < 2; ++half) {
    const int qt = half ? (7 - pj) : pj;
    const int q0 = qt * 128;
    const int nt = 2 * qt + 2;

    bf16x8 qf[2][3];
#pragma unroll
    for (int s = 0; s < 2; ++s) {
      const unsigned short* qp =
          qkv + (bT + q0 + s * 64 + w * 16 + lm) * QS_ + h * D_ + lq * 8;
      qf[s][0] = *(const bf16x8*)(qp);
      qf[s][1] = *(const bf16x8*)(qp + 32);
      qf[s][2] = *(const bf16x8*)(qp + 64);
    }
    f32x4 o[2][7];
#pragma unroll
    for (int s = 0; s < 2; ++s)
#pragma unroll
      for (int i = 0; i < 7; ++i) o[s][i] = (f32x4){0.f, 0.f, 0.f, 0.f};

    for (int jt = 0; jt < nt; ++jt) {
      __syncthreads();
      if (jt + 1 < nt)     issue((jt + 1) * 64, cur ^ 1);
      else if (half == 0)  issue(0, cur ^ 1);

      // per-sub causal state: 0=full, 1=diag (nb/w mask), 2=masked
      const int d0 = (jt == 2 * qt) ? 1 : ((jt == 2 * qt + 1) ? 2 : 0);
      const int d1 = (jt == 2 * qt + 1) ? 1 : 0;

#pragma unroll
      for (int nb = 0; nb < 4; ++nb) {
        bf16x8 kf0 = *(const bf16x8*)&KV[cur][(0 * 4 + nb) * 512 + l * 8];
        bf16x8 kf1 = *(const bf16x8*)&KV[cur][(1 * 4 + nb) * 512 + l * 8];
        bf16x8 kf2 = *(const bf16x8*)&KV[cur][(2 * 4 + nb) * 512 + l * 8];
#pragma unroll
        for (int s = 0; s < 2; ++s) {
          const int ds = s ? d1 : d0;
          if (ds == 2 || (ds == 1 && nb > w)) {
#pragma unroll
            for (int r = 0; r < 4; ++r)
              Pt[s][w][lq * 4 + r][nb * 16 + lm] = 0;
            continue;
          }
          f32x4 a = (f32x4){0.f, 0.f, 0.f, 0.f};
          a = __builtin_amdgcn_mfma_f32_16x16x32_bf16(qf[s][0], kf0, a, 0, 0, 0);
          a = __builtin_amdgcn_mfma_f32_16x16x32_bf16(qf[s][1], kf1, a, 0, 0, 0);
          a = __builtin_amdgcn_mfma_f32_16x16x32_bf16(qf[s][2], kf2, a, 0, 0, 0);
#pragma unroll
          for (int r = 0; r < 4; ++r) {
            float sv = a[r];
            if (ds == 1 && (nb * 16 + lm > w * 16 + lq * 4 + r)) sv = -INFINITY;
            Pt[s][w][lq * 4 + r][nb * 16 + lm] = f2bf(__expf(sv));
          }
        }
      }

      bf16x8 pf[2][2];
#pragma unroll
      for (int s = 0; s < 2; ++s) {
        pf[s][0] = *(const bf16x8*)&Pt[s][w][lm][lq * 8];
        pf[s][1] = *(const bf16x8*)&Pt[s][w][lm][32 + lq * 8];
      }
#pragma unroll
      for (int db = 0; db < 6; ++db) {
        bf16x8 vf0 = *(const bf16x8*)&KV[cur][(12 + db * 2 + 0) * 512 + l * 8];
        bf16x8 vf1 = *(const bf16x8*)&KV[cur][(12 + db * 2 + 1) * 512 + l * 8];
#pragma unroll
        for (int s = 0; s < 2; ++s) {
          o[s][db] = __builtin_amdgcn_mfma_f32_16x16x32_bf16(pf[s][0], vf0, o[s][db], 0, 0, 0);
          o[s][db] = __builtin_amdgcn_mfma_f32_16x16x32_bf16(pf[s][1], vf1, o[s][db], 0, 0, 0);
        }
      }
#pragma unroll
      for (int s = 0; s < 2; ++s) {
        o[s][6] = __builtin_amdgcn_mfma_f32_16x16x32_bf16(pf[s][0], onef, o[s][6], 0, 0, 0);
        o[s][6] = __builtin_amdgcn_mfma_f32_16x16x32_bf16(pf[s][1], onef, o[s][6], 0, 0, 0);
      }
      cur ^= 1;
    }

#pragma unroll
    for (int s = 0; s < 2; ++s)
#pragma unroll
      for (int r = 0; r < 4; ++r) {
        const float inv = 1.f / o[s][6][r];
        const size_t row = bT + q0 + s * 64 + w * 16 + lq * 4 + r;
#pragma unroll
        for (int db = 0; db < 6; ++db)
          y[row * C_ + h * D_ + db * 16 + lm] = f2bf(o[s][db][r] * inv);
      }
  }
}

// ---------------------------------------------------------------------------
extern "C" void kernel_launch(void* const* d_in, const int* in_sizes, int n_in,
                              void* d_out, int out_size, void* d_ws, size_t ws_size,
                              hipStream_t stream) {
  const float* x      = (const float*)d_in[0];
  const float* W_attn = (const float*)d_in[1];
  const float* b_attn = (const float*)d_in[2];
  const float* W_proj = (const float*)d_in[3];
  const float* b_proj = (const float*)d_in[4];
  float* out = (float*)d_out;

  // workspace (55.0 MB): qkv stride 1536 (V lives in vt), yb aliases xb
  // (xb dead after QKV; attn writes yb strictly after QKV, same stream).
  char* ws = (char*)d_ws;
  unsigned short* xb  = (unsigned short*)(ws);                    // 12.58 MB
  unsigned short* WaT = (unsigned short*)(ws + 12582912);         //  3.54 MB
  unsigned short* WpT = (unsigned short*)(ws + 16121856);         //  1.18 MB
  unsigned short* qkv = (unsigned short*)(ws + 17301504);         // 25.17 MB
  unsigned short* vt  = (unsigned short*)(ws + 42467328);         // 12.58 MB
  unsigned short* yb  = xb;                                       // alias

  const float qscale = 0.10206207261596577f;  // 1/sqrt(96)

  // fused prep: x cast (6144 blocks) + both W transposes (2304 blocks)
  prep_kernel<<<6144 + 2304, 256, 0, stream>>>(x, xb, W_attn, WaT, W_proj, WpT);

  // qkv = x @ W_attn + b_attn: 128x128 tiles, 2-buffer 32KB, 1152 blocks
  gemm_mfma_kernel<false, true><<<(N1_ / 128) * (M_ / 128), 256, 0, stream>>>(
      xb, WaT, b_attn, qkv, vt, QS_, C_, qscale, 63, 6);
  // attn: q-quad blocks, 4 pj x 64 bh = 256 blocks, bh = id & 63
  attn_mfma_kernel<<<4 * B_ * H_, 256, 0, stream>>>(qkv, vt, yb);
  // proj: 128x128 tiles, 64m x 6n = 384 blocks
  gemm_mfma_kernel<true, false><<<(C_ / 128) * (M_ / 128), 256, 0, stream>>>(
      yb, WpT, b_proj, out, nullptr, C_, 0, 1.f, 63, 6);
}

// Round 10
// 186.013 us; speedup vs baseline: 1.0090x; 1.0090x over previous
//
#include <hip/hip_runtime.h>
#include <math.h>

#define B_ 8
#define T_ 1024
#define C_ 768
#define H_ 8
#define D_ 96
#define M_ (B_ * T_)     // 8192 tokens
#define N1_ (3 * C_)     // 2304
#define KD_ 768          // K of both GEMMs
#define QS_ 1536         // qkv row stride (Q+K only; V lives in vt)

typedef __bf16 bf16x8 __attribute__((ext_vector_type(8)));
typedef float f32x4 __attribute__((ext_vector_type(4)));
typedef float f32x16 __attribute__((ext_vector_type(16)));

__device__ __forceinline__ unsigned short f2bf(float f) {
  unsigned int u = __float_as_uint(f);
  u += 0x7FFF + ((u >> 16) & 1);          // round-to-nearest-even
  return (unsigned short)(u >> 16);
}

// async global->LDS, 16B per lane; LDS dest = uniform base + lane*16
__device__ __forceinline__ void load_lds16(const void* g, void* l) {
  __builtin_amdgcn_global_load_lds(
      (const __attribute__((address_space(1))) unsigned int*)g,
      (__attribute__((address_space(3))) unsigned int*)l, 16, 0, 0);
}

// ---------------------------------------------------------------------------
// Fused prep: blocks 0..6143 cast x to bf16 (1024 elems each);
// blocks 6144.. transpose W_attn / W_proj to [N][K] bf16.
// ---------------------------------------------------------------------------
__global__ __launch_bounds__(256) void prep_kernel(
    const float* __restrict__ x, unsigned short* __restrict__ xb,
    const float* __restrict__ Wa, unsigned short* __restrict__ WaT,
    const float* __restrict__ Wp, unsigned short* __restrict__ WpT) {
  __shared__ float Lt[32][33];
  int bid = blockIdx.x;
  if (bid < 6144) {
    int i = (bid * 256 + threadIdx.x) * 4;
    float4 v = *(const float4*)(x + i);
    ushort4 o;
    o.x = f2bf(v.x); o.y = f2bf(v.y); o.z = f2bf(v.z); o.w = f2bf(v.w);
    *(ushort4*)(xb + i) = o;
    return;
  }
  bid -= 6144;
  const float* W; unsigned short* WT; int Nd;
  if (bid < 1728) { W = Wa; WT = WaT; Nd = N1_; }
  else            { W = Wp; WT = WpT; Nd = C_; bid -= 1728; }
  const int r0 = (bid % 24) * 32;   // Kd
  const int c0 = (bid / 24) * 32;   // Nd
#pragma unroll
  for (int i = 0; i < 4; ++i) {
    int e = threadIdx.x + 256 * i;
    int r = e >> 5, c = e & 31;
    Lt[r][c] = W[(size_t)(r0 + r) * Nd + c0 + c];
  }
  __syncthreads();
#pragma unroll
  for (int i = 0; i < 4; ++i) {
    int e = threadIdx.x + 256 * i;
    int rr = e >> 5, cc = e & 31;
    WT[(size_t)(c0 + rr) * KD_ + r0 + cc] = f2bf(Lt[cc][rr]);
  }
}

// ---------------------------------------------------------------------------
// R18 GEMM: BK=64 + FULL-CACHE-LINE staging. R16 A/B evidence: residency
// null (occ 15->26%, dur flat), L2 throughput at 25% of ceiling, conflicts
// 0 -> remaining suspects are per-request cost (R16: 16 half-line 64B
// requests per 1KB load) and per-K-step drain cost (24 vmcnt(0)+barrier).
// One change attacks both: BK=64 -> each 1KB wave-load = 8 rows x 128B
// (full lines, half the requests) and 12 K-steps (half the drains).
//  - LDS rows now 128B: bank start = slot*4 (row*128B == 0 mod 32 banks).
//    XOR slot = q ^ (R&7) spreads 8 slots x 4 rows -> known 4-WAY conflict
//    (~1.58x on ~96cyc of ds_read -- cheap vs the ~2000cyc step).
//  - Both-sides involution (rule #21): global chunk lane l = (l&7)^(l>>3)
//    [R&7 == l>>3 within an 8-row load]; frag read slot q ^ (l31&7).
//  - 2 buffers x 32KB = 64KB LDS -> 2 blocks/CU (== R16's measured
//    residency, clean A/B). Per K-step: stage next (8 loads/wave), 4 kh x
//    4 MFMA from cur, vmcnt(0), barrier.
// Used for BOTH GEMMs (QKV: VSCAT scatters V cols to vt; proj: OUTF32).
// C/D frag: col = lane&31, row = (r&3)+8*(r>>2)+4*(lane>>5)  [m74/m101].
// ---------------------------------------------------------------------------
template <bool OUTF32, bool VSCAT>
__global__ __launch_bounds__(256, 4) void gemm_mfma_kernel(
    const unsigned short* __restrict__ A, const unsigned short* __restrict__ Bt,
    const float* __restrict__ bias, void* __restrict__ Cout,
    unsigned short* __restrict__ vt, int N,
    int sc_lim, float sc, int mmask, int mshift) {
  constexpr int LPW = 8;               // 1KB loads per wave per buffer
  __shared__ __align__(16) unsigned short Sb[2][16384];  // 2 x 32 KB
  const int tid = threadIdx.x;
  const int w = tid >> 6, l = tid & 63;
  const int l31 = l & 31, lh = l >> 5;
  const int bid = blockIdx.x;
  const int m0 = (bid & mmask) * 128, n0 = (bid >> mshift) * 128;
  const int wrb = (w >> 1) * 2;        // wave A-block base (32-row units)
  const int wnb = (w & 1) * 2;         // wave B-block base

  f32x16 acc[2][2];
#pragma unroll
  for (int i = 0; i < 2; ++i)
#pragma unroll
    for (int j = 0; j < 2; ++j)
#pragma unroll
      for (int r = 0; r < 16; ++r) acc[i][j][r] = 0.f;

  // staging: load c (= w*8+i) covers 8 rows [(c&15)*8, +8) of A (c<16) or
  // B (c>=16). lane l -> row +(l>>3), global 16B chunk (l&7)^(l>>3)
  // (pre-swizzled source; LDS dest lane-linear -> LDS row 128B, slot
  // s holds chunk s^(R&7)). Advance 64 ushorts (128B) per K-tile.
  const unsigned short* gp[LPW];
#pragma unroll
  for (int i = 0; i < LPW; ++i) {
    const int c = w * LPW + i;
    const int rr = (c & 15) * 8 + (l >> 3);
    const int ck = 8 * ((l & 7) ^ (l >> 3));
    gp[i] = (c < 16) ? A  + (size_t)(m0 + rr) * KD_ + ck
                     : Bt + (size_t)(n0 + rr) * KD_ + ck;
  }

  // prologue: stage tile 0 into buffer 0 (8 loads/wave in flight)
#pragma unroll
  for (int i = 0; i < LPW; ++i) {
    load_lds16(gp[i], &Sb[0][(w * LPW + i) * 512 + l * 8]);
    gp[i] += 64;
  }
  asm volatile("s_waitcnt vmcnt(0)" ::: "memory");
  __builtin_amdgcn_s_barrier();
  asm volatile("" ::: "memory");

  const int rx7 = l31 & 7;             // R&7 (XOR term for frag reads)

  int cur = 0;
  for (int t = 0; t < 12; ++t) {
    const bool more = (t + 1 < 12);
    if (more) {
#pragma unroll
      for (int i = 0; i < LPW; ++i) {
        load_lds16(gp[i], &Sb[cur ^ 1][(w * LPW + i) * 512 + l * 8]);
        gp[i] += 64;
      }
    }

#pragma unroll
    for (int kh = 0; kh < 4; ++kh) {
      const int slot = ((kh * 2 + lh) ^ rx7) * 8;
      bf16x8 af[2], bfr[2];
#pragma unroll
      for (int mi = 0; mi < 2; ++mi)
        af[mi] = *(const bf16x8*)
            &Sb[cur][((wrb + mi) * 32 + l31) * 64 + slot];
#pragma unroll
      for (int ni = 0; ni < 2; ++ni)
        bfr[ni] = *(const bf16x8*)
            &Sb[cur][8192 + ((wnb + ni) * 32 + l31) * 64 + slot];
#pragma unroll
      for (int mi = 0; mi < 2; ++mi)
#pragma unroll
        for (int ni = 0; ni < 2; ++ni)
          acc[mi][ni] = __builtin_amdgcn_mfma_f32_32x32x16_bf16(
              af[mi], bfr[ni], acc[mi][ni], 0, 0, 0);
    }

    if (more) {
      asm volatile("s_waitcnt vmcnt(0)" ::: "memory");
      asm volatile("" ::: "memory");
      __builtin_amdgcn_s_barrier();
      asm volatile("" ::: "memory");
    }
    cur ^= 1;
  }

  const bool vblock = VSCAT && (n0 >= 1536);
#pragma unroll
  for (int mi = 0; mi < 2; ++mi) {
    const int rowb = m0 + (wrb + mi) * 32 + 4 * lh;
#pragma unroll
    for (int ni = 0; ni < 2; ++ni) {
      const int col = n0 + (wnb + ni) * 32 + l31;
      const float bv = bias[col];
      if (!vblock) {
        const float mul = (col < sc_lim) ? sc : 1.f;
#pragma unroll
        for (int r = 0; r < 16; ++r) {
          const int row = rowb + (r & 3) + 8 * (r >> 2);
          float v = (acc[mi][ni][r] + bv) * mul;
          if (OUTF32)
            ((float*)Cout)[(size_t)row * N + col] = v;
          else
            ((unsigned short*)Cout)[(size_t)row * N + col] = f2bf(v);
        }
      } else {
        const int x = col - 1536;
        const int h = x / 96, d = x % 96;
#pragma unroll
        for (int r = 0; r < 16; ++r) {
          const int row = rowb + (r & 3) + 8 * (r >> 2);
          const int bb = row >> 10, t = row & 1023;
          vt[((size_t)(bb * H_ + h) * D_ + d) * T_ + t] =
              f2bf(acc[mi][ni][r] + bv);
        }
      }
    }
  }
}

// ---------------------------------------------------------------------------
// Flash causal attention (R16 version, reverted from R17's q-quad which
// regressed +3us): bf16 MFMA 16x16x32, max-free softmax (Q pre-scaled),
// l via ones-MFMA, paired q-tiles (17 key-tiles/block), K/V dbuf LDS.
// ---------------------------------------------------------------------------
__global__ __launch_bounds__(256) void attn_mfma_kernel(
    const unsigned short* __restrict__ qkv,  // [8192][QS_], Q pre-scaled
    const unsigned short* __restrict__ vt,   // [64][96][1024]
    unsigned short* __restrict__ y) {        // [8192][768]
  __shared__ __align__(16) unsigned short KV[2][24 * 512];  // 48 KB
  __shared__ __align__(16) unsigned short Pt[4][16][72];    // pad 64->72

  const int tid = threadIdx.x;
  const int w = tid >> 6, l = tid & 63;
  const int lm = l & 15, lq = l >> 4;
  const int bh = blockIdx.x & 63, pi = blockIdx.x >> 6;
  const int b = bh >> 3, h = bh & 7;
  const size_t bT = (size_t)b * T_;

  bf16x8 onef;
#pragma unroll
  for (int i = 0; i < 8; ++i) onef[i] = (__bf16)1.0f;

  auto issue = [&](int j0, int buf) {
#pragma unroll
    for (int i = 0; i < 6; ++i) {
      const int c = w * 6 + i;
      const unsigned short* g;
      if (c < 12) {
        const int kc = c >> 2, nb = c & 3;
        g = qkv + (bT + j0 + nb * 16 + lm) * QS_ + C_ + h * D_ + kc * 32 + lq * 8;
      } else {
        const int cv = c - 12;
        const int db = cv >> 1, vc = cv & 1;
        g = vt + ((size_t)bh * D_ + db * 16 + lm) * T_ + j0 + vc * 32 + lq * 8;
      }
      load_lds16(g, &KV[buf][c * 512]);
    }
  };

  int cur = 0;
  issue(0, 0);

  for (int half = 0; half < 2; ++half) {
    const int qt = half ? (15 - pi) : pi;
    const int q0 = qt * 64;

    bf16x8 qf[3];
    {
      const unsigned short* qp =
          qkv + (bT + q0 + w * 16 + lm) * QS_ + h * D_ + lq * 8;
      qf[0] = *(const bf16x8*)(qp);
      qf[1] = *(const bf16x8*)(qp + 32);
      qf[2] = *(const bf16x8*)(qp + 64);
    }
    f32x4 o[7];
#pragma unroll
    for (int i = 0; i < 7; ++i) o[i] = (f32x4){0.f, 0.f, 0.f, 0.f};

    for (int jt = 0; jt <= qt; ++jt) {
      __syncthreads();
      if (jt < qt)          issue((jt + 1) * 64, cur ^ 1);
      else if (half == 0)   issue(0, cur ^ 1);

      const bool diag = (jt == qt);
#pragma unroll
      for (int nb = 0; nb < 4; ++nb) {
        if (diag && nb > w) {
#pragma unroll
          for (int r = 0; r < 4; ++r)
            Pt[w][lq * 4 + r][nb * 16 + lm] = 0;
          continue;
        }
        f32x4 a = (f32x4){0.f, 0.f, 0.f, 0.f};
#pragma unroll
        for (int kc = 0; kc < 3; ++kc) {
          bf16x8 kf = *(const bf16x8*)&KV[cur][(kc * 4 + nb) * 512 + l * 8];
          a = __builtin_amdgcn_mfma_f32_16x16x32_bf16(qf[kc], kf, a, 0, 0, 0);
        }
#pragma unroll
        for (int r = 0; r < 4; ++r) {
          float s = a[r];
          if (diag && (nb * 16 + lm > w * 16 + lq * 4 + r)) s = -INFINITY;
          Pt[w][lq * 4 + r][nb * 16 + lm] = f2bf(__expf(s));
        }
      }

      bf16x8 pf0 = *(const bf16x8*)&Pt[w][lm][lq * 8];
      bf16x8 pf1 = *(const bf16x8*)&Pt[w][lm][32 + lq * 8];
#pragma unroll
      for (int db = 0; db < 6; ++db) {
        bf16x8 vf0 = *(const bf16x8*)&KV[cur][(12 + db * 2 + 0) * 512 + l * 8];
        bf16x8 vf1 = *(const bf16x8*)&KV[cur][(12 + db * 2 + 1) * 512 + l * 8];
        o[db] = __builtin_amdgcn_mfma_f32_16x16x32_bf16(pf0, vf0, o[db], 0, 0, 0);
        o[db] = __builtin_amdgcn_mfma_f32_16x16x32_bf16(pf1, vf1, o[db], 0, 0, 0);
      }
      o[6] = __builtin_amdgcn_mfma_f32_16x16x32_bf16(pf0, onef, o[6], 0, 0, 0);
      o[6] = __builtin_amdgcn_mfma_f32_16x16x32_bf16(pf1, onef, o[6], 0, 0, 0);
      cur ^= 1;
    }

#pragma unroll
    for (int r = 0; r < 4; ++r) {
      const float inv = 1.f / o[6][r];
      const size_t row = bT + q0 + w * 16 + lq * 4 + r;
#pragma unroll
      for (int db = 0; db < 6; ++db)
        y[row * C_ + h * D_ + db * 16 + lm] = f2bf(o[db][r] * inv);
    }
  }
}

// ---------------------------------------------------------------------------
extern "C" void kernel_launch(void* const* d_in, const int* in_sizes, int n_in,
                              void* d_out, int out_size, void* d_ws, size_t ws_size,
                              hipStream_t stream) {
  const float* x      = (const float*)d_in[0];
  const float* W_attn = (const float*)d_in[1];
  const float* b_attn = (const float*)d_in[2];
  const float* W_proj = (const float*)d_in[3];
  const float* b_proj = (const float*)d_in[4];
  float* out = (float*)d_out;

  // workspace (55.0 MB): qkv stride 1536 (V lives in vt), yb aliases xb
  // (xb dead after QKV; attn writes yb strictly after QKV, same stream).
  char* ws = (char*)d_ws;
  unsigned short* xb  = (unsigned short*)(ws);                    // 12.58 MB
  unsigned short* WaT = (unsigned short*)(ws + 12582912);         //  3.54 MB
  unsigned short* WpT = (unsigned short*)(ws + 16121856);         //  1.18 MB
  unsigned short* qkv = (unsigned short*)(ws + 17301504);         // 25.17 MB
  unsigned short* vt  = (unsigned short*)(ws + 42467328);         // 12.58 MB
  unsigned short* yb  = xb;                                       // alias

  const float qscale = 0.10206207261596577f;  // 1/sqrt(96)

  // fused prep: x cast (6144 blocks) + both W transposes (2304 blocks)
  prep_kernel<<<6144 + 2304, 256, 0, stream>>>(x, xb, W_attn, WaT, W_proj, WpT);

  // qkv = x @ W_attn + b_attn: 128x128 tiles, BK=64 full-line staging
  gemm_mfma_kernel<false, true><<<(N1_ / 128) * (M_ / 128), 256, 0, stream>>>(
      xb, WaT, b_attn, qkv, vt, QS_, C_, qscale, 63, 6);
  // attn: q-pair blocks, 512 blocks, bh = id & 63 for XCD locality
  attn_mfma_kernel<<<8 * B_ * H_, 256, 0, stream>>>(qkv, vt, yb);
  // proj: 128x128 tiles, 64m x 6n = 384 blocks
  gemm_mfma_kernel<true, false><<<(C_ / 128) * (M_ / 128), 256, 0, stream>>>(
      yb, WpT, b_proj, out, nullptr, C_, 0, 1.f, 63, 6);
}

// Round 11
// 183.252 us; speedup vs baseline: 1.0242x; 1.0151x over previous
//
#include <hip/hip_runtime.h>
#include <math.h>

#define B_ 8
#define T_ 1024
#define C_ 768
#define H_ 8
#define D_ 96
#define M_ (B_ * T_)     // 8192 tokens
#define N1_ (3 * C_)     // 2304
#define KD_ 768          // K of both GEMMs
#define QS_ 1536         // qkv row stride (Q+K only; V lives in vt)

typedef __bf16 bf16x8 __attribute__((ext_vector_type(8)));
typedef float f32x4 __attribute__((ext_vector_type(4)));
typedef float f32x16 __attribute__((ext_vector_type(16)));

__device__ __forceinline__ unsigned short f2bf(float f) {
  unsigned int u = __float_as_uint(f);
  u += 0x7FFF + ((u >> 16) & 1);          // round-to-nearest-even
  return (unsigned short)(u >> 16);
}

// async global->LDS, 16B per lane; LDS dest = uniform base + lane*16
__device__ __forceinline__ void load_lds16(const void* g, void* l) {
  __builtin_amdgcn_global_load_lds(
      (const __attribute__((address_space(1))) unsigned int*)g,
      (__attribute__((address_space(3))) unsigned int*)l, 16, 0, 0);
}

// ---------------------------------------------------------------------------
// Fused prep: blocks 0..6143 cast x to bf16 (1024 elems each);
// blocks 6144.. transpose W_attn / W_proj to [N][K] bf16.
// ---------------------------------------------------------------------------
__global__ __launch_bounds__(256) void prep_kernel(
    const float* __restrict__ x, unsigned short* __restrict__ xb,
    const float* __restrict__ Wa, unsigned short* __restrict__ WaT,
    const float* __restrict__ Wp, unsigned short* __restrict__ WpT) {
  __shared__ float Lt[32][33];
  int bid = blockIdx.x;
  if (bid < 6144) {
    int i = (bid * 256 + threadIdx.x) * 4;
    float4 v = *(const float4*)(x + i);
    ushort4 o;
    o.x = f2bf(v.x); o.y = f2bf(v.y); o.z = f2bf(v.z); o.w = f2bf(v.w);
    *(ushort4*)(xb + i) = o;
    return;
  }
  bid -= 6144;
  const float* W; unsigned short* WT; int Nd;
  if (bid < 1728) { W = Wa; WT = WaT; Nd = N1_; }
  else            { W = Wp; WT = WpT; Nd = C_; bid -= 1728; }
  const int r0 = (bid % 24) * 32;   // Kd
  const int c0 = (bid / 24) * 32;   // Nd
#pragma unroll
  for (int i = 0; i < 4; ++i) {
    int e = threadIdx.x + 256 * i;
    int r = e >> 5, c = e & 31;
    Lt[r][c] = W[(size_t)(r0 + r) * Nd + c0 + c];
  }
  __syncthreads();
#pragma unroll
  for (int i = 0; i < 4; ++i) {
    int e = threadIdx.x + 256 * i;
    int rr = e >> 5, cc = e & 31;
    WT[(size_t)(c0 + rr) * KD_ + r0 + cc] = f2bf(Lt[cc][rr]);
  }
}

// ---------------------------------------------------------------------------
// R19 split: per-shape GEMM configs. R18's BK=64 full-line kernel won -6us
// on QKV but its inheritance by proj cost +7.5us (rest-of-pipeline delta
// R16->R18) -- proj's 384-block grid wants 4 blocks/CU (32KB) and pays the
// 8-way-conflict tax over 1/3 the work. QKV keeps BK=64; proj reverts to
// the R16 BK=32 config verbatim.
// ---------------------------------------------------------------------------

// --- QKV GEMM: BK=64, full-cache-line staging (R18, proven 45.4us) -------
// Staging: load c = w*8+i covers 8 rows x 128B (full lines). Lane l -> row
// +(l>>3), global 16B chunk (l&7)^(l>>3); LDS dest lane-linear (128B rows,
// slot s of row R holds chunk s^(R&7)). Frag read slot q^(R&7): known
// structural 8-way conflict (3.5M cyc, ~12% -- b128 on 128B rows can only
// hit 8 bank-group starts). 2 bufs x 32KB, 12 K-steps, vmcnt(0)+barrier.
// C/D frag: col = lane&31, row = (r&3)+8*(r>>2)+4*(lane>>5)  [m74/m101].
template <bool OUTF32, bool VSCAT>
__global__ __launch_bounds__(256, 4) void gemm64_kernel(
    const unsigned short* __restrict__ A, const unsigned short* __restrict__ Bt,
    const float* __restrict__ bias, void* __restrict__ Cout,
    unsigned short* __restrict__ vt, int N,
    int sc_lim, float sc, int mmask, int mshift) {
  constexpr int LPW = 8;               // 1KB loads per wave per buffer
  __shared__ __align__(16) unsigned short Sb[2][16384];  // 2 x 32 KB
  const int tid = threadIdx.x;
  const int w = tid >> 6, l = tid & 63;
  const int l31 = l & 31, lh = l >> 5;
  const int bid = blockIdx.x;
  const int m0 = (bid & mmask) * 128, n0 = (bid >> mshift) * 128;
  const int wrb = (w >> 1) * 2;        // wave A-block base (32-row units)
  const int wnb = (w & 1) * 2;         // wave B-block base

  f32x16 acc[2][2];
#pragma unroll
  for (int i = 0; i < 2; ++i)
#pragma unroll
    for (int j = 0; j < 2; ++j)
#pragma unroll
      for (int r = 0; r < 16; ++r) acc[i][j][r] = 0.f;

  const unsigned short* gp[LPW];
#pragma unroll
  for (int i = 0; i < LPW; ++i) {
    const int c = w * LPW + i;
    const int rr = (c & 15) * 8 + (l >> 3);
    const int ck = 8 * ((l & 7) ^ (l >> 3));
    gp[i] = (c < 16) ? A  + (size_t)(m0 + rr) * KD_ + ck
                     : Bt + (size_t)(n0 + rr) * KD_ + ck;
  }

  // prologue: stage tile 0 into buffer 0 (8 loads/wave in flight)
#pragma unroll
  for (int i = 0; i < LPW; ++i) {
    load_lds16(gp[i], &Sb[0][(w * LPW + i) * 512 + l * 8]);
    gp[i] += 64;
  }
  asm volatile("s_waitcnt vmcnt(0)" ::: "memory");
  __builtin_amdgcn_s_barrier();
  asm volatile("" ::: "memory");

  const int rx7 = l31 & 7;             // R&7 (XOR term for frag reads)

  int cur = 0;
  for (int t = 0; t < 12; ++t) {
    const bool more = (t + 1 < 12);
    if (more) {
#pragma unroll
      for (int i = 0; i < LPW; ++i) {
        load_lds16(gp[i], &Sb[cur ^ 1][(w * LPW + i) * 512 + l * 8]);
        gp[i] += 64;
      }
    }

#pragma unroll
    for (int kh = 0; kh < 4; ++kh) {
      const int slot = ((kh * 2 + lh) ^ rx7) * 8;
      bf16x8 af[2], bfr[2];
#pragma unroll
      for (int mi = 0; mi < 2; ++mi)
        af[mi] = *(const bf16x8*)
            &Sb[cur][((wrb + mi) * 32 + l31) * 64 + slot];
#pragma unroll
      for (int ni = 0; ni < 2; ++ni)
        bfr[ni] = *(const bf16x8*)
            &Sb[cur][8192 + ((wnb + ni) * 32 + l31) * 64 + slot];
#pragma unroll
      for (int mi = 0; mi < 2; ++mi)
#pragma unroll
        for (int ni = 0; ni < 2; ++ni)
          acc[mi][ni] = __builtin_amdgcn_mfma_f32_32x32x16_bf16(
              af[mi], bfr[ni], acc[mi][ni], 0, 0, 0);
    }

    if (more) {
      asm volatile("s_waitcnt vmcnt(0)" ::: "memory");
      asm volatile("" ::: "memory");
      __builtin_amdgcn_s_barrier();
      asm volatile("" ::: "memory");
    }
    cur ^= 1;
  }

  const bool vblock = VSCAT && (n0 >= 1536);
#pragma unroll
  for (int mi = 0; mi < 2; ++mi) {
    const int rowb = m0 + (wrb + mi) * 32 + 4 * lh;
#pragma unroll
    for (int ni = 0; ni < 2; ++ni) {
      const int col = n0 + (wnb + ni) * 32 + l31;
      const float bv = bias[col];
      if (!vblock) {
        const float mul = (col < sc_lim) ? sc : 1.f;
#pragma unroll
        for (int r = 0; r < 16; ++r) {
          const int row = rowb + (r & 3) + 8 * (r >> 2);
          float v = (acc[mi][ni][r] + bv) * mul;
          if (OUTF32)
            ((float*)Cout)[(size_t)row * N + col] = v;
          else
            ((unsigned short*)Cout)[(size_t)row * N + col] = f2bf(v);
        }
      } else {
        const int x = col - 1536;
        const int h = x / 96, d = x % 96;
#pragma unroll
        for (int r = 0; r < 16; ++r) {
          const int row = rowb + (r & 3) + 8 * (r >> 2);
          const int bb = row >> 10, t = row & 1023;
          vt[((size_t)(bb * H_ + h) * D_ + d) * T_ + t] =
              f2bf(acc[mi][ni][r] + bv);
        }
      }
    }
  }
}

// --- proj GEMM: BK=32, 64B-segment staging (R16 verbatim; 0 conflicts,
// 32KB LDS -> 4 blocks/CU; best measured config for the 384-block shape) --
template <bool OUTF32, bool VSCAT>
__global__ __launch_bounds__(256, 4) void gemm32_kernel(
    const unsigned short* __restrict__ A, const unsigned short* __restrict__ Bt,
    const float* __restrict__ bias, void* __restrict__ Cout,
    unsigned short* __restrict__ vt, int N,
    int sc_lim, float sc, int mmask, int mshift) {
  constexpr int CPW = 4;               // chunks staged per wave
  __shared__ __align__(16) unsigned short Sb[2][16 * 512];  // 2 x 16 KB
  const int tid = threadIdx.x;
  const int w = tid >> 6, l = tid & 63;
  const int l31 = l & 31, lh = l >> 5;
  const int bid = blockIdx.x;
  const int m0 = (bid & mmask) * 128, n0 = (bid >> mshift) * 128;
  const int wrb = (w >> 1) * 2;        // wave A-block base (32-row units)
  const int wnb = (w & 1) * 2;         // wave B-block base

  f32x16 acc[2][2];
#pragma unroll
  for (int i = 0; i < 2; ++i)
#pragma unroll
    for (int j = 0; j < 2; ++j)
#pragma unroll
      for (int r = 0; r < 16; ++r) acc[i][j][r] = 0.f;

  const unsigned short* gp[CPW];
#pragma unroll
  for (int i = 0; i < CPW; ++i) {
    const int c = w * CPW + i;
    const int rr = (c & 7) * 16 + (l >> 2);
    const int ck = 8 * ((l & 3) ^ ((l >> 4) & 3));
    gp[i] = (c < 8) ? A  + (size_t)(m0 + rr) * KD_ + ck
                    : Bt + (size_t)(n0 + rr) * KD_ + ck;
  }

  // prologue: stage tile 0 into buffer 0
#pragma unroll
  for (int i = 0; i < CPW; ++i) {
    load_lds16(gp[i], &Sb[0][(w * CPW + i) * 512]);
    gp[i] += 32;
  }
  asm volatile("s_waitcnt vmcnt(0)" ::: "memory");
  __builtin_amdgcn_s_barrier();
  asm volatile("" ::: "memory");

  const int rhi = l31 >> 4;            // (R&31)>>4
  const int rlo = (l31 & 15) * 32;     // (R&15)*32 ushorts
  const int rx  = (l31 >> 2) & 3;      // (R>>2)&3 (XOR term)

  int cur = 0;
  for (int k0 = 0; k0 < KD_; k0 += 32) {
    const bool more = (k0 + 32 < KD_);
    if (more) {
#pragma unroll
      for (int i = 0; i < CPW; ++i) {
        load_lds16(gp[i], &Sb[cur ^ 1][(w * CPW + i) * 512]);
        gp[i] += 32;
      }
    }

#pragma unroll
    for (int kh = 0; kh < 2; ++kh) {
      const int q = 2 * kh + lh;       // 16B chunk index within 64B row
      bf16x8 af[2], bfr[2];
#pragma unroll
      for (int mi = 0; mi < 2; ++mi)
        af[mi] = *(const bf16x8*)
            &Sb[cur][((wrb + mi) * 2 + rhi) * 512 + rlo + ((q ^ rx)) * 8];
#pragma unroll
      for (int ni = 0; ni < 2; ++ni)
        bfr[ni] = *(const bf16x8*)
            &Sb[cur][(8 + (wnb + ni) * 2 + rhi) * 512 + rlo + ((q ^ rx)) * 8];
#pragma unroll
      for (int mi = 0; mi < 2; ++mi)
#pragma unroll
        for (int ni = 0; ni < 2; ++ni)
          acc[mi][ni] = __builtin_amdgcn_mfma_f32_32x32x16_bf16(
              af[mi], bfr[ni], acc[mi][ni], 0, 0, 0);
    }

    if (more) {
      asm volatile("s_waitcnt vmcnt(0)" ::: "memory");
      asm volatile("" ::: "memory");
      __builtin_amdgcn_s_barrier();
      asm volatile("" ::: "memory");
    }
    cur ^= 1;
  }

  const bool vblock = VSCAT && (n0 >= 1536);
#pragma unroll
  for (int mi = 0; mi < 2; ++mi) {
    const int rowb = m0 + (wrb + mi) * 32 + 4 * lh;
#pragma unroll
    for (int ni = 0; ni < 2; ++ni) {
      const int col = n0 + (wnb + ni) * 32 + l31;
      const float bv = bias[col];
      if (!vblock) {
        const float mul = (col < sc_lim) ? sc : 1.f;
#pragma unroll
        for (int r = 0; r < 16; ++r) {
          const int row = rowb + (r & 3) + 8 * (r >> 2);
          float v = (acc[mi][ni][r] + bv) * mul;
          if (OUTF32)
            ((float*)Cout)[(size_t)row * N + col] = v;
          else
            ((unsigned short*)Cout)[(size_t)row * N + col] = f2bf(v);
        }
      } else {
        const int x = col - 1536;
        const int h = x / 96, d = x % 96;
#pragma unroll
        for (int r = 0; r < 16; ++r) {
          const int row = rowb + (r & 3) + 8 * (r >> 2);
          const int bb = row >> 10, t = row & 1023;
          vt[((size_t)(bb * H_ + h) * D_ + d) * T_ + t] =
              f2bf(acc[mi][ni][r] + bv);
        }
      }
    }
  }
}

// ---------------------------------------------------------------------------
// Flash causal attention (R16 version): bf16 MFMA 16x16x32, max-free
// softmax (Q pre-scaled), l via ones-MFMA, paired q-tiles, K/V dbuf LDS.
// ---------------------------------------------------------------------------
__global__ __launch_bounds__(256) void attn_mfma_kernel(
    const unsigned short* __restrict__ qkv,  // [8192][QS_], Q pre-scaled
    const unsigned short* __restrict__ vt,   // [64][96][1024]
    unsigned short* __restrict__ y) {        // [8192][768]
  __shared__ __align__(16) unsigned short KV[2][24 * 512];  // 48 KB
  __shared__ __align__(16) unsigned short Pt[4][16][72];    // pad 64->72

  const int tid = threadIdx.x;
  const int w = tid >> 6, l = tid & 63;
  const int lm = l & 15, lq = l >> 4;
  const int bh = blockIdx.x & 63, pi = blockIdx.x >> 6;
  const int b = bh >> 3, h = bh & 7;
  const size_t bT = (size_t)b * T_;

  bf16x8 onef;
#pragma unroll
  for (int i = 0; i < 8; ++i) onef[i] = (__bf16)1.0f;

  auto issue = [&](int j0, int buf) {
#pragma unroll
    for (int i = 0; i < 6; ++i) {
      const int c = w * 6 + i;
      const unsigned short* g;
      if (c < 12) {
        const int kc = c >> 2, nb = c & 3;
        g = qkv + (bT + j0 + nb * 16 + lm) * QS_ + C_ + h * D_ + kc * 32 + lq * 8;
      } else {
        const int cv = c - 12;
        const int db = cv >> 1, vc = cv & 1;
        g = vt + ((size_t)bh * D_ + db * 16 + lm) * T_ + j0 + vc * 32 + lq * 8;
      }
      load_lds16(g, &KV[buf][c * 512]);
    }
  };

  int cur = 0;
  issue(0, 0);

  for (int half = 0; half < 2; ++half) {
    const int qt = half ? (15 - pi) : pi;
    const int q0 = qt * 64;

    bf16x8 qf[3];
    {
      const unsigned short* qp =
          qkv + (bT + q0 + w * 16 + lm) * QS_ + h * D_ + lq * 8;
      qf[0] = *(const bf16x8*)(qp);
      qf[1] = *(const bf16x8*)(qp + 32);
      qf[2] = *(const bf16x8*)(qp + 64);
    }
    f32x4 o[7];
#pragma unroll
    for (int i = 0; i < 7; ++i) o[i] = (f32x4){0.f, 0.f, 0.f, 0.f};

    for (int jt = 0; jt <= qt; ++jt) {
      __syncthreads();
      if (jt < qt)          issue((jt + 1) * 64, cur ^ 1);
      else if (half == 0)   issue(0, cur ^ 1);

      const bool diag = (jt == qt);
#pragma unroll
      for (int nb = 0; nb < 4; ++nb) {
        if (diag && nb > w) {
#pragma unroll
          for (int r = 0; r < 4; ++r)
            Pt[w][lq * 4 + r][nb * 16 + lm] = 0;
          continue;
        }
        f32x4 a = (f32x4){0.f, 0.f, 0.f, 0.f};
#pragma unroll
        for (int kc = 0; kc < 3; ++kc) {
          bf16x8 kf = *(const bf16x8*)&KV[cur][(kc * 4 + nb) * 512 + l * 8];
          a = __builtin_amdgcn_mfma_f32_16x16x32_bf16(qf[kc], kf, a, 0, 0, 0);
        }
#pragma unroll
        for (int r = 0; r < 4; ++r) {
          float s = a[r];
          if (diag && (nb * 16 + lm > w * 16 + lq * 4 + r)) s = -INFINITY;
          Pt[w][lq * 4 + r][nb * 16 + lm] = f2bf(__expf(s));
        }
      }

      bf16x8 pf0 = *(const bf16x8*)&Pt[w][lm][lq * 8];
      bf16x8 pf1 = *(const bf16x8*)&Pt[w][lm][32 + lq * 8];
#pragma unroll
      for (int db = 0; db < 6; ++db) {
        bf16x8 vf0 = *(const bf16x8*)&KV[cur][(12 + db * 2 + 0) * 512 + l * 8];
        bf16x8 vf1 = *(const bf16x8*)&KV[cur][(12 + db * 2 + 1) * 512 + l * 8];
        o[db] = __builtin_amdgcn_mfma_f32_16x16x32_bf16(pf0, vf0, o[db], 0, 0, 0);
        o[db] = __builtin_amdgcn_mfma_f32_16x16x32_bf16(pf1, vf1, o[db], 0, 0, 0);
      }
      o[6] = __builtin_amdgcn_mfma_f32_16x16x32_bf16(pf0, onef, o[6], 0, 0, 0);
      o[6] = __builtin_amdgcn_mfma_f32_16x16x32_bf16(pf1, onef, o[6], 0, 0, 0);
      cur ^= 1;
    }

#pragma unroll
    for (int r = 0; r < 4; ++r) {
      const float inv = 1.f / o[6][r];
      const size_t row = bT + q0 + w * 16 + lq * 4 + r;
#pragma unroll
      for (int db = 0; db < 6; ++db)
        y[row * C_ + h * D_ + db * 16 + lm] = f2bf(o[db][r] * inv);
    }
  }
}

// ---------------------------------------------------------------------------
extern "C" void kernel_launch(void* const* d_in, const int* in_sizes, int n_in,
                              void* d_out, int out_size, void* d_ws, size_t ws_size,
                              hipStream_t stream) {
  const float* x      = (const float*)d_in[0];
  const float* W_attn = (const float*)d_in[1];
  const float* b_attn = (const float*)d_in[2];
  const float* W_proj = (const float*)d_in[3];
  const float* b_proj = (const float*)d_in[4];
  float* out = (float*)d_out;

  // workspace (55.0 MB): qkv stride 1536 (V lives in vt), yb aliases xb
  // (xb dead after QKV; attn writes yb strictly after QKV, same stream).
  char* ws = (char*)d_ws;
  unsigned short* xb  = (unsigned short*)(ws);                    // 12.58 MB
  unsigned short* WaT = (unsigned short*)(ws + 12582912);         //  3.54 MB
  unsigned short* WpT = (unsigned short*)(ws + 16121856);         //  1.18 MB
  unsigned short* qkv = (unsigned short*)(ws + 17301504);         // 25.17 MB
  unsigned short* vt  = (unsigned short*)(ws + 42467328);         // 12.58 MB
  unsigned short* yb  = xb;                                       // alias

  const float qscale = 0.10206207261596577f;  // 1/sqrt(96)

  // fused prep: x cast (6144 blocks) + both W transposes (2304 blocks)
  prep_kernel<<<6144 + 2304, 256, 0, stream>>>(x, xb, W_attn, WaT, W_proj, WpT);

  // qkv = x @ W_attn + b_attn: 128x128 tiles, BK=64 full-line staging
  gemm64_kernel<false, true><<<(N1_ / 128) * (M_ / 128), 256, 0, stream>>>(
      xb, WaT, b_attn, qkv, vt, QS_, C_, qscale, 63, 6);
  // attn: q-pair blocks, 512 blocks, bh = id & 63 for XCD locality
  attn_mfma_kernel<<<8 * B_ * H_, 256, 0, stream>>>(qkv, vt, yb);
  // proj: 128x128 tiles, BK=32 config (best measured for 384-block shape)
  gemm32_kernel<true, false><<<(C_ / 128) * (M_ / 128), 256, 0, stream>>>(
      yb, WpT, b_proj, out, nullptr, C_, 0, 1.f, 63, 6);
}